// Round 1
// baseline (277.012 us; speedup 1.0000x reference)
//
#include <hip/hip_runtime.h>
#include <hip/hip_bf16.h>
#include <cstdint>

#define DEVI static __device__ __forceinline__

typedef __attribute__((ext_vector_type(8))) short short8v;  // 8 bf16 (4 VGPRs)
typedef __attribute__((ext_vector_type(4))) float f32x4;

DEVI ushort f2bf(float f) {  // fp32 -> bf16, round-to-nearest-even
  union { float f; uint32_t u; } v; v.f = f;
  uint32_t r = v.u + 0x7FFFu + ((v.u >> 16) & 1u);
  return (ushort)(r >> 16);
}

// ---------------- projection kernel ----------------
// grid: (32 pos-tiles of 128, 5 row-groups, 4 batch), block 256.
// og==0: q rows (waves 0,1) + k rows (waves 2,3) -> qT/kT position-major bf16 [B][N][32]
// og 1..4: v rows (og-1)*64 + wave*16 -> v channel-major bf16 [B][256][N]
__global__ __launch_bounds__(256, 3) void proj_kernel(
    const float* __restrict__ x,
    const float* __restrict__ Wq, const float* __restrict__ bq,
    const float* __restrict__ Wk, const float* __restrict__ bk,
    const float* __restrict__ Wv, const float* __restrict__ bv,
    ushort* __restrict__ qT, ushort* __restrict__ kT, ushort* __restrict__ vO)
{
  const int lane = threadIdx.x & 63;
  const int wv = __builtin_amdgcn_readfirstlane(threadIdx.x >> 6);
  const int og = blockIdx.y, b = blockIdx.z;
  const int i = blockIdx.x * 128 + lane * 2;

  const float* W; const float* bias; int row0;
  if (og == 0) {
    if (wv < 2) { W = Wq; bias = bq; row0 = wv * 16; }
    else        { W = Wk; bias = bk; row0 = (wv - 2) * 16; }
  } else {
    W = Wv; bias = bv; row0 = (og - 1) * 64 + wv * 16;
  }

  float2 acc[16];
  #pragma unroll
  for (int r = 0; r < 16; ++r) { float bz = bias[row0 + r]; acc[r].x = bz; acc[r].y = bz; }

  const float2* xp = (const float2*)(x + (size_t)b * 256 * 4096 + i);
  #pragma unroll 4
  for (int c = 0; c < 256; ++c) {
    float2 xv = xp[(size_t)c * 2048];
    #pragma unroll
    for (int r = 0; r < 16; ++r) {
      float wq = W[(row0 + r) * 256 + c];
      acc[r].x = fmaf(wq, xv.x, acc[r].x);
      acc[r].y = fmaf(wq, xv.y, acc[r].y);
    }
  }

  if (og == 0) {
    ushort* dst = ((wv < 2) ? qT : kT) + ((size_t)b * 4096 + i) * 32 + row0;
    alignas(16) ushort tmp[16];
    #pragma unroll
    for (int r = 0; r < 16; ++r) tmp[r] = f2bf(acc[r].x);
    *(uint4*)(dst)     = *(const uint4*)(tmp);
    *(uint4*)(dst + 8) = *(const uint4*)(tmp + 8);
    #pragma unroll
    for (int r = 0; r < 16; ++r) tmp[r] = f2bf(acc[r].y);
    *(uint4*)(dst + 32) = *(const uint4*)(tmp);
    *(uint4*)(dst + 40) = *(const uint4*)(tmp + 8);
  } else {
    #pragma unroll
    for (int r = 0; r < 16; ++r) {
      ushort2 o2; o2.x = f2bf(acc[r].x); o2.y = f2bf(acc[r].y);
      *(ushort2*)(vO + ((size_t)b * 256 + row0 + r) * 4096 + i) = o2;
    }
  }
}

// ---------------- fused flash attention ----------------
// grid: (64 q-tiles of 64, 4 batch), block 256 (4 waves).
// Wave w: computes S^T/softmax for qi-subtile w (rows q0+w*16..+15, no duplication),
// and PV for ALL 64 qi rows x c-slice [w*64, w*64+64). P and per-tile rescale
// factors are exchanged through double-buffered LDS (one barrier per k-tile).
// MFMA k-slot map chosen as g*8+j for both operands => all fragments are
// contiguous 16B loads (only the verified C/D layout matters).
__global__ __launch_bounds__(256, 1) void attn_kernel(
    const ushort* __restrict__ qT, const ushort* __restrict__ kT,
    const ushort* __restrict__ vB,
    const float* __restrict__ x, const float* __restrict__ gamma,
    float* __restrict__ out, float* __restrict__ wsp)
{
  __shared__ alignas(16) ushort Plds[2][64 * 64];  // [buf][qi][kj], XOR-swizzled rows
  __shared__ alignas(16) float Slds[2][64];        // per-row rescale factor
  __shared__ alignas(16) float Llds[64];           // final softmax denominators

  const int lane = threadIdx.x & 63;
  const int w = __builtin_amdgcn_readfirstlane(threadIdx.x >> 6);
  const int g = lane >> 4, m16 = lane & 15;
  const int b = blockIdx.y, q0 = blockIdx.x * 64;
  const int cb = w * 64;
  const float L2E = 1.44269504f;
  const size_t bN = (size_t)b * 4096;

  // Q fragment for this wave's subtile (hoisted)
  short8v qf = *(const short8v*)(qT + (bN + q0 + w * 16 + m16) * 32 + g * 8);

  f32x4 acc[4][4];  // [qi-subtile][c-subtile]
  f32x4 zz = {0.f, 0.f, 0.f, 0.f};
  #pragma unroll
  for (int t = 0; t < 4; ++t)
    #pragma unroll
    for (int ct = 0; ct < 4; ++ct) acc[t][ct] = zz;

  float mrun = -3.0e38f, lsum = 0.f;

  short8v kfA[4], kfB[4];
  #pragma unroll
  for (int j = 0; j < 4; ++j)
    kfA[j] = *(const short8v*)(kT + (bN + j * 16 + m16) * 32 + g * 8);

  auto body = [&](int kt, short8v (&kfc)[4], short8v (&kfn)[4]) {
    const int kb = kt * 64, buf = kt & 1;
    const int knb = (kt < 63) ? kb + 64 : kb;
    // prefetch next K-tile fragments (consumed next iteration)
    #pragma unroll
    for (int j = 0; j < 4; ++j)
      kfn[j] = *(const short8v*)(kT + (bN + knb + j * 16 + m16) * 32 + g * 8);
    // V fragments for this tile (consumed after the barrier -> latency hidden)
    short8v vf[4][2];
    #pragma unroll
    for (int ct = 0; ct < 4; ++ct)
      #pragma unroll
      for (int h = 0; h < 2; ++h)
        vf[ct][h] = *(const short8v*)(vB + ((size_t)(b * 256 + cb + ct * 16 + m16)) * 4096
                                      + kb + h * 32 + g * 8);
    // S^T = K_tile * Q : D rows = kj (g*4+r per kjt), cols = qi (m16)
    float s[16];
    #pragma unroll
    for (int j = 0; j < 4; ++j) {
      f32x4 z = {0.f, 0.f, 0.f, 0.f};
      f32x4 s4 = __builtin_amdgcn_mfma_f32_16x16x32_bf16(kfc[j], qf, z, 0, 0, 0);
      s[j*4+0] = s4[0]; s[j*4+1] = s4[1]; s[j*4+2] = s4[2]; s[j*4+3] = s4[3];
    }
    // online softmax for this wave's 16 rows (defer-max, THR=8)
    float m0 = fmaxf(fmaxf(fmaxf(s[0], s[1]), fmaxf(s[2], s[3])),
                     fmaxf(fmaxf(s[4], s[5]), fmaxf(s[6], s[7])));
    float m1 = fmaxf(fmaxf(fmaxf(s[8], s[9]), fmaxf(s[10], s[11])),
                     fmaxf(fmaxf(s[12], s[13]), fmaxf(s[14], s[15])));
    float pmax = fmaxf(m0, m1);
    pmax = fmaxf(pmax, __shfl_xor(pmax, 16));
    pmax = fmaxf(pmax, __shfl_xor(pmax, 32));
    float sc = 1.0f;
    if (__ballot(pmax > mrun + 8.0f)) {
      float mnew = fmaxf(mrun, pmax);
      sc = exp2f((mrun - mnew) * L2E);
      lsum *= sc;
      mrun = mnew;
    }
    if (g == 0) Slds[buf][w * 16 + m16] = sc;
    const float ml = mrun * L2E;
    float p[16], ps = 0.f;
    #pragma unroll
    for (int j2 = 0; j2 < 16; ++j2) { p[j2] = exp2f(fmaf(s[j2], L2E, -ml)); ps += p[j2]; }
    lsum += ps;
    {  // write P rows (swizzled: byte ^= (row&7)<<4 within the 128B row)
      const int qi = w * 16 + m16;
      char* pb = (char*)Plds + buf * 8192 + qi * 128;
      const uint32_t Mr = (uint32_t)((qi & 7) << 4);
      #pragma unroll
      for (int j = 0; j < 4; ++j) {
        uint2 val;
        val.x = (uint32_t)f2bf(p[j*4+0]) | ((uint32_t)f2bf(p[j*4+1]) << 16);
        val.y = (uint32_t)f2bf(p[j*4+2]) | ((uint32_t)f2bf(p[j*4+3]) << 16);
        *(uint2*)(pb + ((uint32_t)(j * 32 + g * 8) ^ Mr)) = val;
      }
    }
    __syncthreads();
    // apply communicated rescale (usually 1.0 -> skipped)
    f32x4 scv[4];
    #pragma unroll
    for (int t = 0; t < 4; ++t) scv[t] = *(const f32x4*)&Slds[buf][t * 16 + g * 4];
    int needmul = 0;
    #pragma unroll
    for (int t = 0; t < 4; ++t)
      #pragma unroll
      for (int r = 0; r < 4; ++r) needmul |= (scv[t][r] != 1.0f);
    if (__ballot(needmul)) {
      #pragma unroll
      for (int t = 0; t < 4; ++t)
        #pragma unroll
        for (int ct = 0; ct < 4; ++ct)
          #pragma unroll
          for (int r = 0; r < 4; ++r) acc[t][ct][r] *= scv[t][r];
    }
    // PV: A = P rows (from LDS, swizzled 16B reads), B = V fragments
    const char* pbr = (const char*)Plds + buf * 8192;
    const uint32_t Mr2 = (uint32_t)((m16 & 7) << 4);
    #pragma unroll
    for (int t = 0; t < 4; ++t) {
      #pragma unroll
      for (int h = 0; h < 2; ++h) {
        short8v pa = *(const short8v*)(pbr + (t * 16 + m16) * 128
                                       + ((uint32_t)(h * 64 + g * 16) ^ Mr2));
        #pragma unroll
        for (int ct = 0; ct < 4; ++ct)
          acc[t][ct] = __builtin_amdgcn_mfma_f32_16x16x32_bf16(pa, vf[ct][h], acc[t][ct], 0, 0, 0);
      }
    }
  };

  #pragma unroll 1
  for (int kt = 0; kt < 64; kt += 2) {
    body(kt, kfA, kfB);
    body(kt + 1, kfB, kfA);
  }

  if (g == 0) Llds[w * 16 + m16] = lsum;
  __syncthreads();

  const float gm = gamma[0];
  float psum[4] = {0.f, 0.f, 0.f, 0.f};
  #pragma unroll
  for (int t = 0; t < 4; ++t) {
    f32x4 Lv = *(const f32x4*)&Llds[t * 16 + g * 4];
    f32x4 rl;
    #pragma unroll
    for (int r = 0; r < 4; ++r) rl[r] = 1.0f / Lv[r];
    #pragma unroll
    for (int ct = 0; ct < 4; ++ct) {
      const int c = cb + ct * 16 + m16;
      #pragma unroll
      for (int r = 0; r < 4; ++r) {
        const int qi = q0 + t * 16 + g * 4 + r;
        const size_t idx = ((size_t)(b * 256 + c)) * 4096 + qi;
        float of = fmaf(gm, acc[t][ct][r] * rl[r], x[idx]);
        out[idx] = of;
        psum[ct] += of;
      }
    }
  }
  #pragma unroll
  for (int ct = 0; ct < 4; ++ct) {
    float P = psum[ct];
    P += __shfl_xor(P, 16);
    P += __shfl_xor(P, 32);
    if (lane < 16)
      wsp[((size_t)(b * 64 + blockIdx.x)) * 256 + cb + ct * 16 + lane] = P;
  }
}

// ---------------- ECA gate ----------------
// grid: B*C blocks of 1 wave. Mean over spatial from per-block partials,
// sigmoid gate, in-place scale of d_out.
__global__ __launch_bounds__(64) void eca_kernel(
    const float* __restrict__ wsp, const float* __restrict__ weca,
    float* __restrict__ out)
{
  const int lane = threadIdx.x;
  const int b = blockIdx.x >> 8, c = blockIdx.x & 255;
  float s = wsp[((size_t)(b * 64 + lane)) * 256 + c];
  #pragma unroll
  for (int o = 32; o >= 1; o >>= 1) s += __shfl_xor(s, o);
  const float y = s * (1.0f / 4096.0f);
  const float gate = 1.0f / (1.0f + expf(-weca[c * 3 + 1] * y));
  float* row = out + ((size_t)(b * 256 + c)) * 4096;
  #pragma unroll 4
  for (int n = lane; n < 4096; n += 64) row[n] *= gate;
}

extern "C" void kernel_launch(void* const* d_in, const int* in_sizes, int n_in,
                              void* d_out, int out_size, void* d_ws, size_t ws_size,
                              hipStream_t stream) {
  const float* x     = (const float*)d_in[0];
  const float* Wq    = (const float*)d_in[1];
  const float* bq    = (const float*)d_in[2];
  const float* Wk    = (const float*)d_in[3];
  const float* bk    = (const float*)d_in[4];
  const float* Wv    = (const float*)d_in[5];
  const float* bv    = (const float*)d_in[6];
  const float* gamma = (const float*)d_in[7];
  const float* weca  = (const float*)d_in[8];
  float* out = (float*)d_out;

  char* ws = (char*)d_ws;
  ushort* qT = (ushort*)(ws);                 // 1 MB  [B][N][32] bf16
  ushort* kT = (ushort*)(ws + (1u << 20));    // 1 MB  [B][N][32] bf16
  ushort* vB = (ushort*)(ws + (2u << 20));    // 8 MB  [B][256][N] bf16
  float* wsp = (float*)(ws + (10u << 20));    // 256 KB [B][64 qblk][256 c] partials

  proj_kernel<<<dim3(32, 5, 4), 256, 0, stream>>>(x, Wq, bq, Wk, bk, Wv, bv, qT, kT, vB);
  attn_kernel<<<dim3(64, 4), 256, 0, stream>>>(qT, kT, vB, x, gamma, out, wsp);
  eca_kernel<<<dim3(1024), 64, 0, stream>>>(wsp, weca, out);
}

// Round 2
// 209.988 us; speedup vs baseline: 1.3192x; 1.3192x over previous
//
#include <hip/hip_runtime.h>
#include <hip/hip_bf16.h>
#include <cstdint>

#define DEVI static __device__ __forceinline__

typedef __attribute__((ext_vector_type(8))) short short8v;  // 8 bf16 (4 VGPRs)
typedef __attribute__((ext_vector_type(4))) float f32x4;

DEVI ushort f2bf(float f) {  // fp32 -> bf16, round-to-nearest-even
  union { float f; uint32_t u; } v; v.f = f;
  uint32_t r = v.u + 0x7FFFu + ((v.u >> 16) & 1u);
  return (ushort)(r >> 16);
}
DEVI float bf2f(ushort u) {
  union { uint32_t u; float f; } v; v.u = ((uint32_t)u) << 16; return v.f;
}

// ---------------- pack weights: stacked bf16 [320][256] + bias [320] ----------------
__global__ __launch_bounds__(64) void pack_w_kernel(
    const float* __restrict__ Wq, const float* __restrict__ bq,
    const float* __restrict__ Wk, const float* __restrict__ bk,
    const float* __restrict__ Wv, const float* __restrict__ bv,
    ushort* __restrict__ WS, float* __restrict__ BS)
{
  const int r = blockIdx.x;      // 0..319: 0-31 q, 32-63 k, 64-319 v
  const int lane = threadIdx.x;  // 0..63
  const float* src; float bsv;
  if (r < 32)      { src = Wq + r * 256;        bsv = bq[r]; }
  else if (r < 64) { src = Wk + (r - 32) * 256; bsv = bk[r - 32]; }
  else             { src = Wv + (r - 64) * 256; bsv = bv[r - 64]; }
  float4 v = *(const float4*)(src + lane * 4);
  ushort4 o; o.x = f2bf(v.x); o.y = f2bf(v.y); o.z = f2bf(v.z); o.w = f2bf(v.w);
  *(ushort4*)(WS + r * 256 + lane * 4) = o;
  if (lane == 0) BS[r] = bsv;
}

// ---------------- projection as MFMA GEMM ----------------
// grid (128 i-tiles of 32, 4 b), block 256 (4 waves).
// Stage x[c][i-tile] -> LDS XT[i][c] bf16 (swizzled), then 20 o-subtiles of 16
// round-robin across waves. q/k (s<4): D=mfma(W,X)->[o rows, i cols], store
// position-major qT/kT[b][i][32]. v (s>=4): D=mfma(X,W)->[i rows, c cols],
// store channel-major vO[b][c][4096] with packed 8B writes (no transpose pass).
__global__ __launch_bounds__(256, 2) void proj_gemm_kernel(
    const float* __restrict__ x, const ushort* __restrict__ WS,
    const float* __restrict__ BS,
    ushort* __restrict__ qT, ushort* __restrict__ kT, ushort* __restrict__ vO)
{
  __shared__ alignas(16) char XT[32 * 512];  // [i][c*2B], byte ^= (i&15)<<4

  const int t = threadIdx.x;
  const int lane = t & 63;
  const int w = __builtin_amdgcn_readfirstlane(t >> 6);
  const int g = lane >> 4, m16 = lane & 15;
  const int b = blockIdx.y;
  const int i0 = blockIdx.x * 32;
  const size_t xb = (size_t)b * 256 * 4096;

  {  // stage: thread t handles i = t&31, c-group (t>>5)*4, 8 k-passes
    const int i = t & 31, cg = t >> 5;
    float vals[8][4];
    #pragma unroll
    for (int k = 0; k < 8; ++k) {
      const int c0 = k * 32 + cg * 4;
      #pragma unroll
      for (int r = 0; r < 4; ++r)
        vals[k][r] = x[xb + (size_t)(c0 + r) * 4096 + i0 + i];
    }
    char* row = XT + i * 512;
    const uint32_t sw = (uint32_t)((i & 15) << 4);
    #pragma unroll
    for (int k = 0; k < 8; ++k) {
      const int c0 = k * 32 + cg * 4;
      uint2 pk;
      pk.x = (uint32_t)f2bf(vals[k][0]) | ((uint32_t)f2bf(vals[k][1]) << 16);
      pk.y = (uint32_t)f2bf(vals[k][2]) | ((uint32_t)f2bf(vals[k][3]) << 16);
      *(uint2*)(row + (((uint32_t)(c0 * 2)) ^ sw)) = pk;
    }
  }
  __syncthreads();

  // B-frags (also used as A for the v case): lane m16 <-> row i, k-slot g*8+j
  short8v xf[2][8];
  {
    const uint32_t sw = (uint32_t)(m16 << 4);
    #pragma unroll
    for (int isub = 0; isub < 2; ++isub) {
      const char* row = XT + (isub * 16 + m16) * 512;
      #pragma unroll
      for (int kt = 0; kt < 8; ++kt)
        xf[isub][kt] = *(const short8v*)(row + (((uint32_t)(kt * 64 + g * 16)) ^ sw));
    }
  }

  const size_t bN = (size_t)b * 4096;
  #pragma unroll
  for (int si = 0; si < 5; ++si) {
    const int s = w + si * 4;  // o-subtile 0..19
    f32x4 acc0 = {0.f, 0.f, 0.f, 0.f}, acc1 = {0.f, 0.f, 0.f, 0.f};
    if (s < 4) {
      #pragma unroll
      for (int kt = 0; kt < 8; ++kt) {
        short8v wf = *(const short8v*)(WS + (s * 16 + m16) * 256 + kt * 32 + g * 8);
        acc0 = __builtin_amdgcn_mfma_f32_16x16x32_bf16(wf, xf[0][kt], acc0, 0, 0, 0);
        acc1 = __builtin_amdgcn_mfma_f32_16x16x32_bf16(wf, xf[1][kt], acc1, 0, 0, 0);
      }
      // D: rows o = s*16+g*4+r, cols i = m16
      float4 bias = *(const float4*)(BS + s * 16 + g * 4);
      ushort* dst = (s < 2) ? qT : kT;
      const int col = (s & 1) * 16 + g * 4;
      #pragma unroll
      for (int isub = 0; isub < 2; ++isub) {
        f32x4 a = isub ? acc1 : acc0;
        uint2 pk;
        pk.x = (uint32_t)f2bf(a[0] + bias.x) | ((uint32_t)f2bf(a[1] + bias.y) << 16);
        pk.y = (uint32_t)f2bf(a[2] + bias.z) | ((uint32_t)f2bf(a[3] + bias.w) << 16);
        *(uint2*)(dst + (bN + i0 + isub * 16 + m16) * 32 + col) = pk;
      }
    } else {
      #pragma unroll
      for (int kt = 0; kt < 8; ++kt) {
        short8v wf = *(const short8v*)(WS + (s * 16 + m16) * 256 + kt * 32 + g * 8);
        acc0 = __builtin_amdgcn_mfma_f32_16x16x32_bf16(xf[0][kt], wf, acc0, 0, 0, 0);
        acc1 = __builtin_amdgcn_mfma_f32_16x16x32_bf16(xf[1][kt], wf, acc1, 0, 0, 0);
      }
      // D: rows i = isub*16+g*4+r, cols c = s*16+m16-64
      const int c = s * 16 + m16 - 64;
      const float bc = BS[s * 16 + m16];
      #pragma unroll
      for (int isub = 0; isub < 2; ++isub) {
        f32x4 a = isub ? acc1 : acc0;
        uint2 pk;
        pk.x = (uint32_t)f2bf(a[0] + bc) | ((uint32_t)f2bf(a[1] + bc) << 16);
        pk.y = (uint32_t)f2bf(a[2] + bc) | ((uint32_t)f2bf(a[3] + bc) << 16);
        *(uint2*)(vO + ((size_t)(b * 256 + c)) * 4096 + i0 + isub * 16 + g * 4) = pk;
      }
    }
  }
}

// ---------------- fused flash attention, kj-split-2 ----------------
// grid 512: bid&7 -> XCD -> (b = xcd>>1, kjh = xcd&1), qt = bid>>3. 2 blocks/CU.
// Each block: q-tile 64, 32 k-tiles (its kj half). Writes UNNORMALIZED O-partial
// (kjh=0 -> fp32 into d_out; kjh=1 -> bf16 into ws) + per-row m,l.
__global__ __launch_bounds__(256, 2) void attn_kernel(
    const ushort* __restrict__ qT, const ushort* __restrict__ kT,
    const ushort* __restrict__ vB,
    float* __restrict__ O0, ushort* __restrict__ O1,
    float* __restrict__ M, float* __restrict__ L)
{
  __shared__ alignas(16) ushort Plds[2][64 * 64];  // [buf][qi][kj], XOR-swizzled rows
  __shared__ alignas(16) float Slds[2][64];        // per-row rescale factor

  const int lane = threadIdx.x & 63;
  const int w = __builtin_amdgcn_readfirstlane(threadIdx.x >> 6);
  const int g = lane >> 4, m16 = lane & 15;
  const int bid = blockIdx.x;
  const int xcd = bid & 7;
  const int b = xcd >> 1, kjh = xcd & 1;
  const int q0 = (bid >> 3) * 64;
  const int kt0 = kjh * 32;
  const int cb = w * 64;
  const float L2E = 1.44269504f;
  const size_t bN = (size_t)b * 4096;

  short8v qf = *(const short8v*)(qT + (bN + q0 + w * 16 + m16) * 32 + g * 8);

  f32x4 acc[4][4];
  f32x4 zz = {0.f, 0.f, 0.f, 0.f};
  #pragma unroll
  for (int t = 0; t < 4; ++t)
    #pragma unroll
    for (int ct = 0; ct < 4; ++ct) acc[t][ct] = zz;

  float mrun = -3.0e38f, lsum = 0.f;

  short8v kfA[4], kfB[4];
  #pragma unroll
  for (int j = 0; j < 4; ++j)
    kfA[j] = *(const short8v*)(kT + (bN + kt0 * 64 + j * 16 + m16) * 32 + g * 8);

  auto body = [&](int kt, short8v (&kfc)[4], short8v (&kfn)[4]) {
    const int kb = kt * 64, buf = kt & 1;
    const int knb = (kt < kt0 + 31) ? kb + 64 : kb;
    #pragma unroll
    for (int j = 0; j < 4; ++j)
      kfn[j] = *(const short8v*)(kT + (bN + knb + j * 16 + m16) * 32 + g * 8);
    short8v vf[4][2];
    #pragma unroll
    for (int ct = 0; ct < 4; ++ct)
      #pragma unroll
      for (int h = 0; h < 2; ++h)
        vf[ct][h] = *(const short8v*)(vB + ((size_t)(b * 256 + cb + ct * 16 + m16)) * 4096
                                      + kb + h * 32 + g * 8);
    float s[16];
    #pragma unroll
    for (int j = 0; j < 4; ++j) {
      f32x4 z = {0.f, 0.f, 0.f, 0.f};
      f32x4 s4 = __builtin_amdgcn_mfma_f32_16x16x32_bf16(kfc[j], qf, z, 0, 0, 0);
      s[j*4+0] = s4[0]; s[j*4+1] = s4[1]; s[j*4+2] = s4[2]; s[j*4+3] = s4[3];
    }
    float m0 = fmaxf(fmaxf(fmaxf(s[0], s[1]), fmaxf(s[2], s[3])),
                     fmaxf(fmaxf(s[4], s[5]), fmaxf(s[6], s[7])));
    float m1 = fmaxf(fmaxf(fmaxf(s[8], s[9]), fmaxf(s[10], s[11])),
                     fmaxf(fmaxf(s[12], s[13]), fmaxf(s[14], s[15])));
    float pmax = fmaxf(m0, m1);
    pmax = fmaxf(pmax, __shfl_xor(pmax, 16));
    pmax = fmaxf(pmax, __shfl_xor(pmax, 32));
    float sc = 1.0f;
    if (__ballot(pmax > mrun + 8.0f)) {
      float mnew = fmaxf(mrun, pmax);
      sc = exp2f((mrun - mnew) * L2E);
      lsum *= sc;
      mrun = mnew;
    }
    if (g == 0) Slds[buf][w * 16 + m16] = sc;
    const float ml = mrun * L2E;
    float p[16], ps = 0.f;
    #pragma unroll
    for (int j2 = 0; j2 < 16; ++j2) { p[j2] = exp2f(fmaf(s[j2], L2E, -ml)); ps += p[j2]; }
    lsum += ps;
    {
      const int qi = w * 16 + m16;
      char* pb = (char*)Plds + buf * 8192 + qi * 128;
      const uint32_t Mr = (uint32_t)((qi & 7) << 4);
      #pragma unroll
      for (int j = 0; j < 4; ++j) {
        uint2 val;
        val.x = (uint32_t)f2bf(p[j*4+0]) | ((uint32_t)f2bf(p[j*4+1]) << 16);
        val.y = (uint32_t)f2bf(p[j*4+2]) | ((uint32_t)f2bf(p[j*4+3]) << 16);
        *(uint2*)(pb + ((uint32_t)(j * 32 + g * 8) ^ Mr)) = val;
      }
    }
    __syncthreads();
    f32x4 scv[4];
    #pragma unroll
    for (int t = 0; t < 4; ++t) scv[t] = *(const f32x4*)&Slds[buf][t * 16 + g * 4];
    int needmul = 0;
    #pragma unroll
    for (int t = 0; t < 4; ++t)
      #pragma unroll
      for (int r = 0; r < 4; ++r) needmul |= (scv[t][r] != 1.0f);
    if (__ballot(needmul)) {
      #pragma unroll
      for (int t = 0; t < 4; ++t)
        #pragma unroll
        for (int ct = 0; ct < 4; ++ct)
          #pragma unroll
          for (int r = 0; r < 4; ++r) acc[t][ct][r] *= scv[t][r];
    }
    const char* pbr = (const char*)Plds + buf * 8192;
    const uint32_t Mr2 = (uint32_t)((m16 & 7) << 4);
    #pragma unroll
    for (int t = 0; t < 4; ++t) {
      #pragma unroll
      for (int h = 0; h < 2; ++h) {
        short8v pa = *(const short8v*)(pbr + (t * 16 + m16) * 128
                                       + ((uint32_t)(h * 64 + g * 16) ^ Mr2));
        #pragma unroll
        for (int ct = 0; ct < 4; ++ct)
          acc[t][ct] = __builtin_amdgcn_mfma_f32_16x16x32_bf16(pa, vf[ct][h], acc[t][ct], 0, 0, 0);
      }
    }
  };

  #pragma unroll 1
  for (int kt = kt0; kt < kt0 + 32; kt += 2) {
    body(kt, kfA, kfB);
    body(kt + 1, kfB, kfA);
  }

  if (g == 0) {
    const size_t mi = (size_t)kjh * 16384 + bN + q0 + w * 16 + m16;
    M[mi] = mrun;
    L[mi] = lsum;
  }
  if (kjh == 0) {
    #pragma unroll
    for (int t = 0; t < 4; ++t)
      #pragma unroll
      for (int ct = 0; ct < 4; ++ct) {
        const int c = cb + ct * 16 + m16;
        const int qi = q0 + t * 16 + g * 4;
        *(f32x4*)(O0 + ((size_t)(b * 256 + c)) * 4096 + qi) = acc[t][ct];
      }
  } else {
    #pragma unroll
    for (int t = 0; t < 4; ++t)
      #pragma unroll
      for (int ct = 0; ct < 4; ++ct) {
        const int c = cb + ct * 16 + m16;
        const int qi = q0 + t * 16 + g * 4;
        uint2 pk;
        pk.x = (uint32_t)f2bf(acc[t][ct][0]) | ((uint32_t)f2bf(acc[t][ct][1]) << 16);
        pk.y = (uint32_t)f2bf(acc[t][ct][2]) | ((uint32_t)f2bf(acc[t][ct][3]) << 16);
        *(uint2*)(O1 + ((size_t)(b * 256 + c)) * 4096 + qi) = pk;
      }
  }
}

// ---------------- LSE-combine + residual + eca partials ----------------
// grid (64, 4): x -> (qt = x>>1 of 128 qi, ch = x&1 of 128 c). NOTE: O0 aliases
// out (d_out); every element is read before written by the same thread.
__global__ __launch_bounds__(256) void combine_kernel(
    const float* O0, const ushort* __restrict__ O1,
    const float* __restrict__ M, const float* __restrict__ L,
    const float* __restrict__ x, const float* __restrict__ gamma,
    float* out, float* __restrict__ wsp)
{
  const int lane = threadIdx.x & 63;
  const int w = __builtin_amdgcn_readfirstlane(threadIdx.x >> 6);
  const int qt = blockIdx.x >> 1, ch = blockIdx.x & 1;
  const int b = blockIdx.y;
  const int qi = qt * 128 + lane * 2;
  const size_t idxq = (size_t)b * 4096 + qi;
  const float L2E = 1.44269504f;

  float2 m0 = *(const float2*)(M + idxq);
  float2 m1 = *(const float2*)(M + 16384 + idxq);
  float2 l0 = *(const float2*)(L + idxq);
  float2 l1 = *(const float2*)(L + 16384 + idxq);
  float mxx = fmaxf(m0.x, m1.x), mxy = fmaxf(m0.y, m1.y);
  float a0x = exp2f((m0.x - mxx) * L2E), a1x = exp2f((m1.x - mxx) * L2E);
  float a0y = exp2f((m0.y - mxy) * L2E), a1y = exp2f((m1.y - mxy) * L2E);
  float invx = 1.0f / (l0.x * a0x + l1.x * a1x);
  float invy = 1.0f / (l0.y * a0y + l1.y * a1y);
  a0x *= invx; a1x *= invx; a0y *= invy; a1y *= invy;
  const float gm = gamma[0];

  #pragma unroll 4
  for (int cc = 0; cc < 32; ++cc) {
    const int c = ch * 128 + w * 32 + cc;
    const size_t row = ((size_t)(b * 256 + c)) * 4096 + qi;
    float2 o0 = *(const float2*)(O0 + row);
    ushort2 o1 = *(const ushort2*)(O1 + row);
    float2 xv = *(const float2*)(x + row);
    float vx = a0x * o0.x + a1x * bf2f(o1.x);
    float vy = a0y * o0.y + a1y * bf2f(o1.y);
    float2 ov;
    ov.x = fmaf(gm, vx, xv.x);
    ov.y = fmaf(gm, vy, xv.y);
    *(float2*)(out + row) = ov;
    float ps = ov.x + ov.y;
    #pragma unroll
    for (int o = 32; o >= 1; o >>= 1) ps += __shfl_xor(ps, o);
    if (lane == 0) wsp[((size_t)b * 32 + qt) * 256 + c] = ps;
  }
}

// ---------------- ECA gate ----------------
__global__ __launch_bounds__(64) void eca_kernel(
    const float* __restrict__ wsp, const float* __restrict__ weca,
    float* __restrict__ out)
{
  const int lane = threadIdx.x;
  const int b = blockIdx.x >> 8, c = blockIdx.x & 255;
  float s = (lane < 32) ? wsp[((size_t)b * 32 + lane) * 256 + c] : 0.f;
  #pragma unroll
  for (int o = 32; o >= 1; o >>= 1) s += __shfl_xor(s, o);
  const float y = s * (1.0f / 4096.0f);
  const float gate = 1.0f / (1.0f + expf(-weca[c * 3 + 1] * y));
  float4* row = (float4*)(out + ((size_t)(b * 256 + c)) * 4096);
  #pragma unroll 4
  for (int it = 0; it < 16; ++it) {
    float4 v = row[lane + it * 64];
    v.x *= gate; v.y *= gate; v.z *= gate; v.w *= gate;
    row[lane + it * 64] = v;
  }
}

extern "C" void kernel_launch(void* const* d_in, const int* in_sizes, int n_in,
                              void* d_out, int out_size, void* d_ws, size_t ws_size,
                              hipStream_t stream) {
  const float* x     = (const float*)d_in[0];
  const float* Wq    = (const float*)d_in[1];
  const float* bq    = (const float*)d_in[2];
  const float* Wk    = (const float*)d_in[3];
  const float* bk    = (const float*)d_in[4];
  const float* Wv    = (const float*)d_in[5];
  const float* bv    = (const float*)d_in[6];
  const float* gamma = (const float*)d_in[7];
  const float* weca  = (const float*)d_in[8];
  float* out = (float*)d_out;

  char* ws = (char*)d_ws;
  ushort* WS = (ushort*)(ws);                    // 160 KB [320][256] bf16
  float*  BS = (float*)(ws + 0x28000);           // 1.3 KB [320] fp32
  ushort* qT = (ushort*)(ws + 0x30000);          // 1 MB  [B][N][32] bf16
  ushort* kT = (ushort*)(ws + 0x130000);         // 1 MB  [B][N][32] bf16
  ushort* vO = (ushort*)(ws + 0x230000);         // 8 MB  [B][256][N] bf16
  ushort* O1 = (ushort*)(ws + 0xA30000);         // 8 MB  [B][256][N] bf16 (kj-half 1)
  float*  M  = (float*)(ws + 0x1230000);         // 128 KB [2][B][N]
  float*  L  = (float*)(ws + 0x1250000);         // 128 KB [2][B][N]
  float*  wsp= (float*)(ws + 0x1270000);         // 128 KB [B][32][256]

  pack_w_kernel<<<dim3(320), 64, 0, stream>>>(Wq, bq, Wk, bk, Wv, bv, WS, BS);
  proj_gemm_kernel<<<dim3(128, 4), 256, 0, stream>>>(x, WS, BS, qT, kT, vO);
  attn_kernel<<<dim3(512), 256, 0, stream>>>(qT, kT, vO, out, O1, M, L);
  combine_kernel<<<dim3(64, 4), 256, 0, stream>>>(out, O1, M, L, x, gamma, out, wsp);
  eca_kernel<<<dim3(1024), 64, 0, stream>>>(wsp, weca, out);
}